// Round 1
// baseline (11613.047 us; speedup 1.0000x reference)
//
#include <hip/hip_runtime.h>
#include <math.h>

// Problem constants (fixed by reference setup)
#define NN 50000
#define EE 400000
#define CINV 32
#define KKEEP 25000          // ceil(0.5*N)
#define SEQL 5
#define HASH_BITS 20
#define HASH_SIZE (1u<<HASH_BITS)
#define HASH_MASK (HASH_SIZE-1u)
#define HEMPTY 0xFFFFFFFFu

__device__ __forceinline__ void atomAddF(float* p, float v){ unsafeAtomicAdd(p, v); }

// ---------------- utility ----------------
__global__ void k_zero(unsigned* __restrict__ p, int n){
  int i = blockIdx.x*256 + threadIdx.x;
  if (i < n) p[i] = 0u;
}
__global__ void k_init_scal(unsigned* scal, unsigned long long* selp){
  scal[0] = 0u;        // mcount
  scal[1] = 0u;        // mask-is-u8 flag
  scal[3] = KKEEP;     // radix-select remaining rank
  selp[0] = 0ull;      // radix-select prefix
}
__global__ void k_hash_init(uint2* tab){
  int i = blockIdx.x*256 + threadIdx.x;
  if (i < (int)HASH_SIZE) tab[i] = make_uint2(HEMPTY, 0u);
}
// mask dtype detector: if any of the first 12500 int32 words is >1, mask is u8 bytes
__global__ void k_detect_mask(const int* __restrict__ mp, unsigned* scal){
  int i = blockIdx.x*256 + threadIdx.x;
  if (i < NN/4){ if ((unsigned)mp[i] > 1u) atomicOr(&scal[1], 1u); }
}
__global__ void k_compact_mask(const void* __restrict__ mp, unsigned* scal, int* __restrict__ mlist){
  int i = blockIdx.x*256 + threadIdx.x;
  if (i >= NN) return;
  int mv = scal[1] ? (int)((const unsigned char*)mp)[i] : ((const int*)mp)[i];
  if (mv){ int p = (int)atomicAdd(&scal[0], 1u); mlist[p] = i; }
}
__global__ void k_copy(const float* __restrict__ s, float* __restrict__ d){
  int i = blockIdx.x*256 + threadIdx.x;
  if (i < NN*64) d[i] = s[i];
}

// ---------------- matmuls ----------------
__global__ void k_mm_h0(const float* __restrict__ X, const float* __restrict__ W, float* __restrict__ Y){
  int idx = blockIdx.x*256 + threadIdx.x;
  if (idx >= NN*64) return;
  int i = idx>>6, f = idx&63;
  const float* xr = &X[i*CINV];
  float acc = 0.f;
  #pragma unroll
  for (int k=0;k<CINV;k++) acc = fmaf(xr[k], W[k*64+f], acc);
  Y[idx] = acc;
}
__global__ void k_mm64(const float* __restrict__ X, const float* __restrict__ W, float* __restrict__ Y){
  int idx = blockIdx.x*256 + threadIdx.x;
  if (idx >= NN*64) return;
  int i = idx>>6, f = idx&63;
  const float* xr = &X[i*64];
  float acc = 0.f;
  #pragma unroll
  for (int k=0;k<64;k++) acc = fmaf(xr[k], W[k*64+f], acc);
  Y[idx] = acc;
}
// hp[i,:] = score[i] * (x1[i,:] @ W1), kept rows only
__global__ void k_mm64s(const float* __restrict__ X, const float* __restrict__ W,
                        const float* __restrict__ sc, const int* __restrict__ kp,
                        float* __restrict__ Y){
  int idx = blockIdx.x*256 + threadIdx.x;
  if (idx >= NN*64) return;
  int i = idx>>6, f = idx&63;
  if (!kp[i]) return;
  const float* xr = &X[i*64];
  float acc = 0.f;
  #pragma unroll
  for (int k=0;k<64;k++) acc = fmaf(xr[k], W[k*64+f], acc);
  Y[idx] = acc * sc[i];
}

// ---------------- GCN pieces ----------------
__global__ void k_degcnt(const int* __restrict__ col, int* __restrict__ degcnt){
  int e = blockIdx.x*256 + threadIdx.x;
  if (e < EE) atomicAdd(&degcnt[col[e]], 1);
}
__global__ void k_dinv0(const int* __restrict__ degcnt, float* __restrict__ dinv){
  int i = blockIdx.x*256 + threadIdx.x;
  if (i < NN) dinv[i] = rsqrtf((float)degcnt[i] + 2.0f);
}
// acc[col] += dinv[row]*H[row]  (edge-parallel, 64 feat lanes per edge)
__global__ void k_gcn_agg(const int* __restrict__ row, const int* __restrict__ col,
                          const float* __restrict__ dinv, const float* __restrict__ H,
                          float* __restrict__ acc){
  int idx = blockIdx.x*256 + threadIdx.x;
  if (idx >= EE*64) return;
  int e = idx>>6, f = idx&63;
  int r = row[e];
  atomAddF(&acc[col[e]*64 + f], dinv[r]*H[r*64+f]);
}
__global__ void k_gcn0_fin(const float* __restrict__ acc, const float* __restrict__ H,
                           const float* __restrict__ dinv, const float* __restrict__ b,
                           float* __restrict__ out){
  int idx = blockIdx.x*256 + threadIdx.x;
  if (idx >= NN*64) return;
  int i = idx>>6, f = idx&63;
  float di = dinv[i];
  float v = di*acc[idx] + 2.f*di*di*H[idx] + b[f];
  out[idx] = fmaxf(v, 0.f);
}
__global__ void k_xofin(const float* __restrict__ acc, const float* __restrict__ H,
                        const float* __restrict__ dinv, const float* __restrict__ b,
                        float* __restrict__ xo, float* __restrict__ out){
  int idx = blockIdx.x*256 + threadIdx.x;
  if (idx >= NN*64) return;
  int i = idx>>6, f = idx&63;
  float di = dinv[i];
  float v = di*acc[idx] + 2.f*di*di*H[idx] + b[f];
  xo[idx] = v; out[idx] = v;
}

// ---------------- TopK selection ----------------
__global__ void k_pwnorm(const float* __restrict__ pw, float* scalf){
  int lane = threadIdx.x;
  float v = pw[lane]*pw[lane];
  for (int o=32;o;o>>=1) v += __shfl_down(v, o, 64);
  if (lane==0) scalf[2] = sqrtf(v);
}
__global__ void k_scorekey(const float* __restrict__ x1, const float* __restrict__ pw,
                           const float* __restrict__ scalf,
                           unsigned long long* __restrict__ keys, float* __restrict__ score){
  int node = blockIdx.x*4 + (threadIdx.x>>6);
  int lane = threadIdx.x & 63;
  if (node >= NN) return;
  float v = x1[node*64+lane]*pw[lane];
  for (int o=32;o;o>>=1) v += __shfl_down(v, o, 64);
  if (lane==0){
    float s = tanhf(v / scalf[2]);
    s = s + 0.0f;                 // canonicalize -0 -> +0 (numpy treats them equal)
    score[node] = s;
    unsigned u = __float_as_uint(s);
    unsigned asc = (u>>31) ? ~u : (u | 0x80000000u);   // ascending order map
    unsigned desc = ~asc;                               // descending score
    keys[node] = (((unsigned long long)desc)<<32) | (unsigned)node;
  }
}
__global__ void k_hist(const unsigned long long* __restrict__ keys, unsigned* __restrict__ hist,
                       const unsigned long long* __restrict__ selp, int round){
  int i = blockIdx.x*256 + threadIdx.x;
  if (i >= NN) return;
  unsigned long long key = keys[i];
  int shift = 48 - 16*round;
  if (round==0 || (key>>(shift+16)) == selp[0])
    atomicAdd(&hist[(unsigned)((key>>shift)&0xFFFFull)], 1u);
}
__global__ void k_pick(const unsigned* __restrict__ hist, unsigned long long* selp, unsigned* scal){
  __shared__ unsigned csum[256];
  int t = threadIdx.x;
  unsigned s = 0;
  for (int j=0;j<256;j++) s += hist[t*256+j];
  csum[t] = s;
  __syncthreads();
  if (t==0){
    unsigned rem = scal[3];
    int chunk = 255;
    for (int c2=0;c2<256;c2++){ unsigned cc=csum[c2]; if (rem>cc) rem-=cc; else { chunk=c2; break; } }
    int bin = chunk*256 + 255;
    for (int b=chunk*256;b<chunk*256+256;b++){ unsigned hv=hist[b]; if (rem>hv) rem-=hv; else { bin=b; break; } }
    selp[0] = (selp[0]<<16) | (unsigned long long)(unsigned)bin;
    scal[3] = rem;
  }
}
__global__ void k_kpmark(const unsigned long long* __restrict__ keys,
                         const unsigned long long* __restrict__ selp, int* __restrict__ kp){
  int i = blockIdx.x*256 + threadIdx.x;
  if (i < NN) kp[i] = (keys[i] <= selp[0]) ? 1 : 0;
}

// ---------------- reverse-edge hash (A^2 diagonal) ----------------
__global__ void k_hash_build(const int* __restrict__ row, const int* __restrict__ col, uint2* __restrict__ tab){
  int e = blockIdx.x*256 + threadIdx.x;
  if (e >= EE) return;
  unsigned key = (unsigned)row[e]*50000u + (unsigned)col[e];
  unsigned h = (key*2654435761u) >> (32-HASH_BITS);
  for(;;){
    unsigned old = atomicCAS(&tab[h].x, HEMPTY, key);
    if (old==HEMPTY || old==key){ atomicAdd(&tab[h].y, 1u); return; }
    h = (h+1)&HASH_MASK;
  }
}
__global__ void k_diag(const int* __restrict__ row, const int* __restrict__ col,
                       const uint2* __restrict__ tab, int* __restrict__ diagint){
  int e = blockIdx.x*256 + threadIdx.x;
  if (e >= EE) return;
  unsigned rkey = (unsigned)col[e]*50000u + (unsigned)row[e];
  unsigned h = (rkey*2654435761u) >> (32-HASH_BITS);
  for(;;){
    unsigned kk = tab[h].x;
    if (kk==rkey){ atomicAdd(&diagint[row[e]], (int)tab[h].y); return; }
    if (kk==HEMPTY) return;
    h = (h+1)&HASH_MASK;
  }
}

// ---------------- pooled-graph degree via two scalar SpMVs ----------------
__global__ void k_ts(const int* __restrict__ row, const int* __restrict__ col,
                     const int* __restrict__ kp, int* __restrict__ ts){
  int idx = blockIdx.x*256 + threadIdx.x;
  if (idx < EE){ if (kp[row[idx]]) atomicAdd(&ts[col[idx]], 1); }
  else { int i = idx-EE; if (i < NN && kp[i]) atomicAdd(&ts[i], 1); }
}
__global__ void k_colsum(const int* __restrict__ row, const int* __restrict__ col,
                         const int* __restrict__ ts, int* __restrict__ cs){
  int idx = blockIdx.x*256 + threadIdx.x;
  if (idx < EE){ int v = ts[row[idx]]; if (v) atomicAdd(&cs[col[idx]], v); }
  else { int i = idx-EE; if (i < NN){ int v = ts[i]; if (v) atomicAdd(&cs[i], v); } }
}
__global__ void k_dinv1(const int* __restrict__ cs, const int* __restrict__ diagint,
                        const int* __restrict__ kp, float* __restrict__ dinv1){
  int i = blockIdx.x*256 + threadIdx.x;
  if (i >= NN) return;
  dinv1[i] = kp[i] ? rsqrtf((float)(cs[i] - diagint[i] - 1) + 2.0f) : 0.f;
}

// ---------------- pooled-graph feature SpMV passes ----------------
__global__ void k_t2(const int* __restrict__ row, const int* __restrict__ col,
                     const int* __restrict__ kp, const float* __restrict__ dinv1,
                     const float* __restrict__ hp, float* __restrict__ t2){
  int idx = blockIdx.x*256 + threadIdx.x;
  if (idx >= (EE+NN)*64) return;
  int e = idx>>6, f = idx&63;
  int r, cdst;
  if (e < EE){ r = row[e]; cdst = col[e]; } else { r = e-EE; cdst = r; }
  if (kp[r]) atomAddF(&t2[cdst*64+f], dinv1[r]*hp[r*64+f]);
}
__global__ void k_agg2(const int* __restrict__ row, const int* __restrict__ col,
                       const float* __restrict__ t2, float* __restrict__ agg){
  int idx = blockIdx.x*256 + threadIdx.x;
  if (idx >= (EE+NN)*64) return;
  int e = idx>>6, f = idx&63;
  int r, cdst;
  if (e < EE){ r = row[e]; cdst = col[e]; } else { r = e-EE; cdst = r; }
  float v = t2[r*64+f];
  if (v != 0.f) atomAddF(&agg[cdst*64+f], v);
}
// y += relu(x2) at kept nodes (x2 from agg minus diagonal correction + self loop)
__global__ void k_y(const float* __restrict__ agg, const float* __restrict__ hp,
                    const float* __restrict__ dinv1, const int* __restrict__ diagint,
                    const int* __restrict__ kp, const float* __restrict__ b1,
                    float* __restrict__ D){
  int idx = blockIdx.x*256 + threadIdx.x;
  if (idx >= NN*64) return;
  int i = idx>>6, f = idx&63;
  if (!kp[i]) return;
  float di = dinv1[i], hv = hp[idx];
  float diag = (float)(diagint[i] + 1);
  float v = di*(agg[idx] - diag*di*hv) + 2.f*di*di*hv + b1[f];
  D[idx] += fmaxf(v, 0.f);
}

// ---------------- fused 5-step LSTM over sliding windows ----------------
// 4 nodes/block (wave per node); weights staged per 64-gate chunk in LDS (stride-65 pad).
__global__ __launch_bounds__(256) void k_lstm(const float* __restrict__ src, float* __restrict__ dst,
                       const int* __restrict__ mlist, const unsigned* __restrict__ scal,
                       const float* __restrict__ wih, const float* __restrict__ whh,
                       const float* __restrict__ bih, const float* __restrict__ bhh){
  int M = (int)scal[0];
  int base = blockIdx.x*4;
  if (base >= M) return;                // block-uniform exit
  int w = threadIdx.x>>6, lane = threadIdx.x&63;
  int m = base + w;
  bool valid = (m < M);
  int node = mlist[valid ? m : base];
  __shared__ float sxt[4][64];
  __shared__ float sh[4][64];
  __shared__ float swih[64][65];
  __shared__ float swhh[64][65];
  float h = 0.f, c = 0.f;
  float bq0 = bih[lane]      + bhh[lane];
  float bq1 = bih[64+lane]   + bhh[64+lane];
  float bq2 = bih[128+lane]  + bhh[128+lane];
  float bq3 = bih[192+lane]  + bhh[192+lane];
  for (int t=0;t<SEQL;t++){
    int ti = node - (SEQL-1) + t;
    sxt[w][lane] = (ti >= 0) ? src[ti*64 + lane] : 0.f;
    sh[w][lane]  = h;
    float g4[4];
    #pragma unroll
    for (int q=0;q<4;q++){
      __syncthreads();                        // protect swih/swhh before overwrite
      int rr = threadIdx.x>>2;
      int kb = (threadIdx.x&3)<<4;
      const float4* gih = (const float4*)&wih[(q*64+rr)*64 + kb];
      const float4* ghh = (const float4*)&whh[(q*64+rr)*64 + kb];
      #pragma unroll
      for (int j=0;j<4;j++){
        float4 a = gih[j], b2 = ghh[j];
        int kk = kb + 4*j;
        swih[rr][kk]=a.x; swih[rr][kk+1]=a.y; swih[rr][kk+2]=a.z; swih[rr][kk+3]=a.w;
        swhh[rr][kk]=b2.x; swhh[rr][kk+1]=b2.y; swhh[rr][kk+2]=b2.z; swhh[rr][kk+3]=b2.w;
      }
      __syncthreads();
      float acc = 0.f;
      #pragma unroll
      for (int k=0;k<64;k++)
        acc += sxt[w][k]*swih[lane][k] + sh[w][k]*swhh[lane][k];
      g4[q] = acc;
    }
    float ig = 1.f/(1.f+expf(-(g4[0]+bq0)));
    float fg = 1.f/(1.f+expf(-(g4[1]+bq1)));
    float gg = tanhf(g4[2]+bq2);
    float og = 1.f/(1.f+expf(-(g4[3]+bq3)));
    c = fg*c + ig*gg;
    h = og*tanhf(c);
    __syncthreads();                          // last chunk's reads done before next t writes
  }
  if (valid) dst[node*64 + lane] = h;
}

// ==========================================================================
extern "C" void kernel_launch(void* const* d_in, const int* in_sizes, int n_in,
                              void* d_out, int out_size, void* d_ws, size_t ws_size,
                              hipStream_t stream) {
  const float* x   = (const float*)d_in[0];
  const int*   ei  = (const int*)d_in[1];
  const int*   row = ei;
  const int*   col = ei + EE;
  const void*  mp  = d_in[2];
  const float* W0  = (const float*)d_in[3];
  const float* b0  = (const float*)d_in[4];
  const float* W1  = (const float*)d_in[5];
  const float* b1  = (const float*)d_in[6];
  const float* pw  = (const float*)d_in[7];
  const float* Wu  = (const float*)d_in[8];
  const float* bu  = (const float*)d_in[9];
  const float* l0wih=(const float*)d_in[10];
  const float* l0whh=(const float*)d_in[11];
  const float* l0bih=(const float*)d_in[12];
  const float* l0bhh=(const float*)d_in[13];
  const float* lfwih=(const float*)d_in[14];
  const float* lfwhh=(const float*)d_in[15];
  const float* lfbih=(const float*)d_in[16];
  const float* lfbhh=(const float*)d_in[17];

  char* wp = (char*)d_ws;
  auto alloc = [&](size_t bytes)->char*{ char* p = wp; wp += ((bytes+255)/256)*256; return p; };
  float* A     = (float*)alloc((size_t)NN*64*4);   // h0 -> t2 -> xoacc
  float* B     = (float*)alloc((size_t)NN*64*4);   // x1acc -> agg -> xo
  float* C     = (float*)alloc((size_t)NN*64*4);   // x1
  float* D     = (float*)alloc((size_t)NN*64*4);   // res/y
  float* Ebuf  = (float*)alloc((size_t)NN*64*4);   // hp -> hy
  float* score = (float*)alloc((size_t)NN*4);
  float* dinv0 = (float*)alloc((size_t)NN*4);
  float* dinv1 = (float*)alloc((size_t)NN*4);
  unsigned long long* keys = (unsigned long long*)alloc((size_t)NN*8);
  int* degcnt  = (int*)alloc((size_t)NN*4);
  int* diagint = (int*)alloc((size_t)NN*4);
  int* ts      = (int*)alloc((size_t)NN*4);
  int* cs      = (int*)alloc((size_t)NN*4);
  int* kp      = (int*)alloc((size_t)NN*4);
  int* mlist   = (int*)alloc((size_t)NN*4);
  uint2* hash  = (uint2*)alloc((size_t)HASH_SIZE*8);
  unsigned* hist=(unsigned*)alloc((size_t)4*65536*4);
  unsigned* scal=(unsigned*)alloc(256);
  unsigned long long* selp = (unsigned long long*)(scal + 4);

  #define GRID1(n) dim3(((n)+255)/256), dim3(256), 0, stream
  const int N64 = NN*64;

  // init
  k_zero<<<GRID1(N64)>>>((unsigned*)B, N64);
  k_zero<<<GRID1(NN)>>>((unsigned*)degcnt, NN);
  k_zero<<<GRID1(NN)>>>((unsigned*)diagint, NN);
  k_zero<<<GRID1(NN)>>>((unsigned*)ts, NN);
  k_zero<<<GRID1(NN)>>>((unsigned*)cs, NN);
  k_zero<<<GRID1(4*65536)>>>(hist, 4*65536);
  k_init_scal<<<dim3(1),dim3(1),0,stream>>>(scal, selp);
  k_hash_init<<<GRID1(HASH_SIZE)>>>(hash);
  k_detect_mask<<<GRID1(NN/4)>>>((const int*)mp, scal);

  // GCN0
  k_mm_h0<<<GRID1(N64)>>>(x, W0, A);
  k_degcnt<<<GRID1(EE)>>>(col, degcnt);
  k_compact_mask<<<GRID1(NN)>>>(mp, scal, mlist);
  k_dinv0<<<GRID1(NN)>>>(degcnt, dinv0);
  k_gcn_agg<<<GRID1(EE*64)>>>(row, col, dinv0, A, B);
  k_gcn0_fin<<<GRID1(N64)>>>(B, A, dinv0, b0, C);

  // TopK selection (set only; labeling is equivariant)
  k_pwnorm<<<dim3(1),dim3(64),0,stream>>>(pw, (float*)scal);
  k_scorekey<<<dim3((NN+3)/4),dim3(256),0,stream>>>(C, pw, (const float*)scal, keys, score);
  for (int r=0;r<4;r++){
    k_hist<<<GRID1(NN)>>>(keys, hist + r*65536, selp, r);
    k_pick<<<dim3(1),dim3(256),0,stream>>>(hist + r*65536, selp, scal);
  }
  k_kpmark<<<GRID1(NN)>>>(keys, selp, kp);

  // (A+I)^2 diagonal via reverse-edge hash
  k_hash_build<<<GRID1(EE)>>>(row, col, hash);
  k_diag<<<GRID1(EE)>>>(row, col, hash, diagint);

  // pooled degree: colsum_c = sum_{r kept} A2[r,c] via two scalar SpMVs
  k_ts<<<GRID1(EE+NN)>>>(row, col, kp, ts);
  k_colsum<<<GRID1(EE+NN)>>>(row, col, ts, cs);
  k_dinv1<<<GRID1(NN)>>>(cs, diagint, kp, dinv1);

  // pooled GCN: hp = (x1*score)@W1 (kept), then two feature SpMV passes
  k_zero<<<GRID1(N64)>>>((unsigned*)A, N64);
  k_zero<<<GRID1(N64)>>>((unsigned*)B, N64);
  k_mm64s<<<GRID1(N64)>>>(C, W1, score, kp, Ebuf);
  k_t2<<<GRID1((EE+NN)*64)>>>(row, col, kp, dinv1, Ebuf, A);
  k_agg2<<<GRID1((EE+NN)*64)>>>(row, col, A, B);

  // res = x1 with masked rows <- LSTM0(x1 windows)
  k_copy<<<GRID1(N64)>>>(C, D);
  k_lstm<<<dim3((NN+3)/4),dim3(256),0,stream>>>(C, D, mlist, scal, l0wih, l0whh, l0bih, l0bhh);

  // y = res + up (x2 written in place at kept nodes)
  k_y<<<GRID1(N64)>>>(B, Ebuf, dinv1, diagint, kp, b1, D);

  // up-GCN (same graph as GCN0, no relu) -> xo (B) and d_out
  k_mm64<<<GRID1(N64)>>>(D, Wu, Ebuf);
  k_zero<<<GRID1(N64)>>>((unsigned*)A, N64);
  k_gcn_agg<<<GRID1(EE*64)>>>(row, col, dinv0, Ebuf, A);
  k_xofin<<<GRID1(N64)>>>(A, Ebuf, dinv0, bu, B, (float*)d_out);

  // final LSTM on xo windows, scatter into d_out masked rows
  k_lstm<<<dim3((NN+3)/4),dim3(256),0,stream>>>(B, (float*)d_out, mlist, scal, lfwih, lfwhh, lfbih, lfbhh);
  #undef GRID1
}

// Round 2
// 1338.404 us; speedup vs baseline: 8.6768x; 8.6768x over previous
//
#include <hip/hip_runtime.h>
#include <math.h>

// Problem constants (fixed by reference setup)
#define NN 50000
#define EE 400000
#define CINV 32
#define KKEEP 25000          // ceil(0.5*N)
#define SEQL 5
#define HASH_BITS 20
#define HASH_SIZE (1u<<HASH_BITS)
#define HASH_MASK (HASH_SIZE-1u)
#define HEMPTY 0xFFFFFFFFu
#define LSTM_G 1024

__device__ __forceinline__ void atomAddF(float* p, float v){ unsafeAtomicAdd(p, v); }
__device__ __forceinline__ float sigm(float x){ return 1.f/(1.f+__expf(-x)); }

// ---------------- utility ----------------
__global__ void k_zero(unsigned* __restrict__ p, int n){
  int i = blockIdx.x*256 + threadIdx.x;
  if (i < n) p[i] = 0u;
}
__global__ void k_init_scal(unsigned* scal, unsigned long long* selp){
  scal[0] = 0u;        // mcount
  scal[1] = 0u;        // mask-is-u8 flag
  scal[3] = KKEEP;     // radix-select remaining rank
  selp[0] = 0ull;      // radix-select prefix
}
__global__ void k_hash_init(uint2* tab){
  int i = blockIdx.x*256 + threadIdx.x;
  if (i < (int)HASH_SIZE) tab[i] = make_uint2(HEMPTY, 0u);
}
// mask dtype detector: if any of the first 12500 int32 words is >1, mask is u8 bytes
__global__ void k_detect_mask(const int* __restrict__ mp, unsigned* scal){
  int i = blockIdx.x*256 + threadIdx.x;
  if (i < NN/4){ if ((unsigned)mp[i] > 1u) atomicOr(&scal[1], 1u); }
}
__global__ void k_compact_mask(const void* __restrict__ mp, unsigned* scal, int* __restrict__ mlist){
  int i = blockIdx.x*256 + threadIdx.x;
  if (i >= NN) return;
  int mv = scal[1] ? (int)((const unsigned char*)mp)[i] : ((const int*)mp)[i];
  if (mv){ int p = (int)atomicAdd(&scal[0], 1u); mlist[p] = i; }
}
__global__ void k_copy(const float* __restrict__ s, float* __restrict__ d){
  int i = blockIdx.x*256 + threadIdx.x;
  if (i < NN*64) d[i] = s[i];
}

// ---------------- matmuls ----------------
__global__ void k_mm_h0(const float* __restrict__ X, const float* __restrict__ W, float* __restrict__ Y){
  int idx = blockIdx.x*256 + threadIdx.x;
  if (idx >= NN*64) return;
  int i = idx>>6, f = idx&63;
  const float* xr = &X[i*CINV];
  float acc = 0.f;
  #pragma unroll
  for (int k=0;k<CINV;k++) acc = fmaf(xr[k], W[k*64+f], acc);
  Y[idx] = acc;
}
__global__ void k_mm64(const float* __restrict__ X, const float* __restrict__ W, float* __restrict__ Y){
  int idx = blockIdx.x*256 + threadIdx.x;
  if (idx >= NN*64) return;
  int i = idx>>6, f = idx&63;
  const float* xr = &X[i*64];
  float acc = 0.f;
  #pragma unroll
  for (int k=0;k<64;k++) acc = fmaf(xr[k], W[k*64+f], acc);
  Y[idx] = acc;
}
// hp[i,:] = score[i] * (x1[i,:] @ W1), kept rows only
__global__ void k_mm64s(const float* __restrict__ X, const float* __restrict__ W,
                        const float* __restrict__ sc, const int* __restrict__ kp,
                        float* __restrict__ Y){
  int idx = blockIdx.x*256 + threadIdx.x;
  if (idx >= NN*64) return;
  int i = idx>>6, f = idx&63;
  if (!kp[i]) return;
  const float* xr = &X[i*64];
  float acc = 0.f;
  #pragma unroll
  for (int k=0;k<64;k++) acc = fmaf(xr[k], W[k*64+f], acc);
  Y[idx] = acc * sc[i];
}

// ---------------- GCN pieces ----------------
__global__ void k_degcnt(const int* __restrict__ col, int* __restrict__ degcnt){
  int e = blockIdx.x*256 + threadIdx.x;
  if (e < EE) atomicAdd(&degcnt[col[e]], 1);
}
__global__ void k_dinv0(const int* __restrict__ degcnt, float* __restrict__ dinv){
  int i = blockIdx.x*256 + threadIdx.x;
  if (i < NN) dinv[i] = rsqrtf((float)degcnt[i] + 2.0f);
}
// acc[col] += dinv[row]*H[row]  (edge-parallel, 64 feat lanes per edge)
__global__ void k_gcn_agg(const int* __restrict__ row, const int* __restrict__ col,
                          const float* __restrict__ dinv, const float* __restrict__ H,
                          float* __restrict__ acc){
  int idx = blockIdx.x*256 + threadIdx.x;
  if (idx >= EE*64) return;
  int e = idx>>6, f = idx&63;
  int r = row[e];
  atomAddF(&acc[col[e]*64 + f], dinv[r]*H[r*64+f]);
}
__global__ void k_gcn0_fin(const float* __restrict__ acc, const float* __restrict__ H,
                           const float* __restrict__ dinv, const float* __restrict__ b,
                           float* __restrict__ out){
  int idx = blockIdx.x*256 + threadIdx.x;
  if (idx >= NN*64) return;
  int i = idx>>6, f = idx&63;
  float di = dinv[i];
  float v = di*acc[idx] + 2.f*di*di*H[idx] + b[f];
  out[idx] = fmaxf(v, 0.f);
}
__global__ void k_xofin(const float* __restrict__ acc, const float* __restrict__ H,
                        const float* __restrict__ dinv, const float* __restrict__ b,
                        float* __restrict__ xo, float* __restrict__ out){
  int idx = blockIdx.x*256 + threadIdx.x;
  if (idx >= NN*64) return;
  int i = idx>>6, f = idx&63;
  float di = dinv[i];
  float v = di*acc[idx] + 2.f*di*di*H[idx] + b[f];
  xo[idx] = v; out[idx] = v;
}

// ---------------- TopK selection ----------------
__global__ void k_pwnorm(const float* __restrict__ pw, float* scalf){
  int lane = threadIdx.x;
  float v = pw[lane]*pw[lane];
  for (int o=32;o;o>>=1) v += __shfl_down(v, o, 64);
  if (lane==0) scalf[2] = sqrtf(v);
}
__global__ void k_scorekey(const float* __restrict__ x1, const float* __restrict__ pw,
                           const float* __restrict__ scalf,
                           unsigned long long* __restrict__ keys, float* __restrict__ score){
  int node = blockIdx.x*4 + (threadIdx.x>>6);
  int lane = threadIdx.x & 63;
  if (node >= NN) return;
  float v = x1[node*64+lane]*pw[lane];
  for (int o=32;o;o>>=1) v += __shfl_down(v, o, 64);
  if (lane==0){
    float s = tanhf(v / scalf[2]);
    s = s + 0.0f;                 // canonicalize -0 -> +0 (numpy treats them equal)
    score[node] = s;
    unsigned u = __float_as_uint(s);
    unsigned asc = (u>>31) ? ~u : (u | 0x80000000u);   // ascending order map
    unsigned desc = ~asc;                               // descending score
    keys[node] = (((unsigned long long)desc)<<32) | (unsigned)node;
  }
}
__global__ void k_hist(const unsigned long long* __restrict__ keys, unsigned* __restrict__ hist,
                       const unsigned long long* __restrict__ selp, int round){
  int i = blockIdx.x*256 + threadIdx.x;
  if (i >= NN) return;
  unsigned long long key = keys[i];
  int shift = 48 - 16*round;
  if (round==0 || (key>>(shift+16)) == selp[0])
    atomicAdd(&hist[(unsigned)((key>>shift)&0xFFFFull)], 1u);
}
__global__ void k_pick(const unsigned* __restrict__ hist, unsigned long long* selp, unsigned* scal){
  __shared__ unsigned csum[256];
  int t = threadIdx.x;
  unsigned s = 0;
  for (int j=0;j<256;j++) s += hist[t*256+j];
  csum[t] = s;
  __syncthreads();
  if (t==0){
    unsigned rem = scal[3];
    int chunk = 255;
    for (int c2=0;c2<256;c2++){ unsigned cc=csum[c2]; if (rem>cc) rem-=cc; else { chunk=c2; break; } }
    int bin = chunk*256 + 255;
    for (int b=chunk*256;b<chunk*256+256;b++){ unsigned hv=hist[b]; if (rem>hv) rem-=hv; else { bin=b; break; } }
    selp[0] = (selp[0]<<16) | (unsigned long long)(unsigned)bin;
    scal[3] = rem;
  }
}
__global__ void k_kpmark(const unsigned long long* __restrict__ keys,
                         const unsigned long long* __restrict__ selp, int* __restrict__ kp){
  int i = blockIdx.x*256 + threadIdx.x;
  if (i < NN) kp[i] = (keys[i] <= selp[0]) ? 1 : 0;
}

// ---------------- reverse-edge hash (A^2 diagonal) ----------------
__global__ void k_hash_build(const int* __restrict__ row, const int* __restrict__ col, uint2* __restrict__ tab){
  int e = blockIdx.x*256 + threadIdx.x;
  if (e >= EE) return;
  unsigned key = (unsigned)row[e]*50000u + (unsigned)col[e];
  unsigned h = (key*2654435761u) >> (32-HASH_BITS);
  for(;;){
    unsigned old = atomicCAS(&tab[h].x, HEMPTY, key);
    if (old==HEMPTY || old==key){ atomicAdd(&tab[h].y, 1u); return; }
    h = (h+1)&HASH_MASK;
  }
}
__global__ void k_diag(const int* __restrict__ row, const int* __restrict__ col,
                       const uint2* __restrict__ tab, int* __restrict__ diagint){
  int e = blockIdx.x*256 + threadIdx.x;
  if (e >= EE) return;
  unsigned rkey = (unsigned)col[e]*50000u + (unsigned)row[e];
  unsigned h = (rkey*2654435761u) >> (32-HASH_BITS);
  for(;;){
    unsigned kk = tab[h].x;
    if (kk==rkey){ atomicAdd(&diagint[row[e]], (int)tab[h].y); return; }
    if (kk==HEMPTY) return;
    h = (h+1)&HASH_MASK;
  }
}

// ---------------- pooled-graph degree via two scalar SpMVs ----------------
__global__ void k_ts(const int* __restrict__ row, const int* __restrict__ col,
                     const int* __restrict__ kp, int* __restrict__ ts){
  int idx = blockIdx.x*256 + threadIdx.x;
  if (idx < EE){ if (kp[row[idx]]) atomicAdd(&ts[col[idx]], 1); }
  else { int i = idx-EE; if (i < NN && kp[i]) atomicAdd(&ts[i], 1); }
}
__global__ void k_colsum(const int* __restrict__ row, const int* __restrict__ col,
                         const int* __restrict__ ts, int* __restrict__ cs){
  int idx = blockIdx.x*256 + threadIdx.x;
  if (idx < EE){ int v = ts[row[idx]]; if (v) atomicAdd(&cs[col[idx]], v); }
  else { int i = idx-EE; if (i < NN){ int v = ts[i]; if (v) atomicAdd(&cs[i], v); } }
}
__global__ void k_dinv1(const int* __restrict__ cs, const int* __restrict__ diagint,
                        const int* __restrict__ kp, float* __restrict__ dinv1){
  int i = blockIdx.x*256 + threadIdx.x;
  if (i >= NN) return;
  dinv1[i] = kp[i] ? rsqrtf((float)(cs[i] - diagint[i] - 1) + 2.0f) : 0.f;
}

// ---------------- pooled-graph feature SpMV passes ----------------
__global__ void k_t2(const int* __restrict__ row, const int* __restrict__ col,
                     const int* __restrict__ kp, const float* __restrict__ dinv1,
                     const float* __restrict__ hp, float* __restrict__ t2){
  int idx = blockIdx.x*256 + threadIdx.x;
  if (idx >= (EE+NN)*64) return;
  int e = idx>>6, f = idx&63;
  int r, cdst;
  if (e < EE){ r = row[e]; cdst = col[e]; } else { r = e-EE; cdst = r; }
  if (kp[r]) atomAddF(&t2[cdst*64+f], dinv1[r]*hp[r*64+f]);
}
__global__ void k_agg2(const int* __restrict__ row, const int* __restrict__ col,
                       const float* __restrict__ t2, float* __restrict__ agg){
  int idx = blockIdx.x*256 + threadIdx.x;
  if (idx >= (EE+NN)*64) return;
  int e = idx>>6, f = idx&63;
  int r, cdst;
  if (e < EE){ r = row[e]; cdst = col[e]; } else { r = e-EE; cdst = r; }
  float v = t2[r*64+f];
  if (v != 0.f) atomAddF(&agg[cdst*64+f], v);
}
// y += relu(x2) at kept nodes (x2 from agg minus diagonal correction + self loop)
__global__ void k_y(const float* __restrict__ agg, const float* __restrict__ hp,
                    const float* __restrict__ dinv1, const int* __restrict__ diagint,
                    const int* __restrict__ kp, const float* __restrict__ b1,
                    float* __restrict__ D){
  int idx = blockIdx.x*256 + threadIdx.x;
  if (idx >= NN*64) return;
  int i = idx>>6, f = idx&63;
  if (!kp[i]) return;
  float di = dinv1[i], hv = hp[idx];
  float diag = (float)(diagint[i] + 1);
  float v = di*(agg[idx] - diag*di*hv) + 2.f*di*di*hv + b1[f];
  D[idx] += fmaxf(v, 0.f);
}

// ---------------- fused 5-step LSTM: persistent weights in registers ----------------
// Wave w owns gate chunk w (torch order i,f,g,o); lane g holds row w*64+g of
// W_ih and W_hh in 32 float4 VGPRs (128 regs). Blocks grid-stride over masked
// node PAIRS; activations broadcast from ~5 KB LDS (wave-uniform reads = free).
__global__ __launch_bounds__(256) void k_lstm(const float* __restrict__ src, float* __restrict__ dst,
                       const int* __restrict__ mlist, const unsigned* __restrict__ scal,
                       const float* __restrict__ wih, const float* __restrict__ whh,
                       const float* __restrict__ bih, const float* __restrict__ bhh){
  int M = (int)scal[0];
  int w = threadIdx.x>>6, lane = threadIdx.x&63;
  int r = w*64 + lane;
  const float4* gih = (const float4*)&wih[r*64];
  const float4* ghh = (const float4*)&whh[r*64];
  float4 wi[16], wh[16];
  #pragma unroll
  for (int j=0;j<16;j++){ wi[j]=gih[j]; wh[j]=ghh[j]; }
  float bq = bih[r] + bhh[r];

  __shared__ float sx[2][SEQL][64];      // [node][t][feat]
  __shared__ float sh[2][64];            // [node][feat]
  __shared__ float gates[2][4][64];      // [node][chunk][elem]

  for (int p = blockIdx.x; 2*p < M; p += LSTM_G){
    int m0 = 2*p, m1 = 2*p+1;
    bool v1 = (m1 < M);
    int n0 = mlist[m0];
    int n1 = v1 ? mlist[m1] : n0;
    // stage both 5-row windows (zero left-pad)
    for (int idx = threadIdx.x; idx < 2*SEQL*64; idx += 256){
      int nd = idx >= SEQL*64;
      int rem = idx - nd*SEQL*64;
      int rr = rem >> 6, ff = rem & 63;
      int node = nd ? n1 : n0;
      int ti = node - (SEQL-1) + rr;
      sx[nd][rr][ff] = (ti >= 0) ? src[ti*64 + ff] : 0.f;
    }
    if (threadIdx.x < 128) sh[threadIdx.x>>6][threadIdx.x&63] = 0.f;
    __syncthreads();
    float c0=0.f, c1=0.f, h0v=0.f, h1v=0.f;
    for (int t=0;t<SEQL;t++){
      float a0 = bq, a1 = bq;
      #pragma unroll
      for (int j=0;j<16;j++){
        float4 x0 = *(const float4*)&sx[0][t][j*4];
        float4 hh0 = *(const float4*)&sh[0][j*4];
        a0 += x0.x*wi[j].x + x0.y*wi[j].y + x0.z*wi[j].z + x0.w*wi[j].w
            + hh0.x*wh[j].x + hh0.y*wh[j].y + hh0.z*wh[j].z + hh0.w*wh[j].w;
        float4 x1 = *(const float4*)&sx[1][t][j*4];
        float4 hh1 = *(const float4*)&sh[1][j*4];
        a1 += x1.x*wi[j].x + x1.y*wi[j].y + x1.z*wi[j].z + x1.w*wi[j].w
            + hh1.x*wh[j].x + hh1.y*wh[j].y + hh1.z*wh[j].z + hh1.w*wh[j].w;
      }
      gates[0][w][lane] = a0;
      gates[1][w][lane] = a1;
      __syncthreads();
      if (w==0){
        float gi=gates[0][0][lane], gf=gates[0][1][lane], gg=gates[0][2][lane], go=gates[0][3][lane];
        c0 = sigm(gf)*c0 + sigm(gi)*tanhf(gg);
        h0v = sigm(go)*tanhf(c0);
        sh[0][lane] = h0v;
        gi=gates[1][0][lane]; gf=gates[1][1][lane]; gg=gates[1][2][lane]; go=gates[1][3][lane];
        c1 = sigm(gf)*c1 + sigm(gi)*tanhf(gg);
        h1v = sigm(go)*tanhf(c1);
        sh[1][lane] = h1v;
      }
      __syncthreads();
    }
    if (w==0){
      dst[n0*64+lane] = h0v;
      if (v1) dst[n1*64+lane] = h1v;
    }
    __syncthreads();   // all waves done with sx/gates before next pair overwrites
  }
}

// ==========================================================================
extern "C" void kernel_launch(void* const* d_in, const int* in_sizes, int n_in,
                              void* d_out, int out_size, void* d_ws, size_t ws_size,
                              hipStream_t stream) {
  const float* x   = (const float*)d_in[0];
  const int*   ei  = (const int*)d_in[1];
  const int*   row = ei;
  const int*   col = ei + EE;
  const void*  mp  = d_in[2];
  const float* W0  = (const float*)d_in[3];
  const float* b0  = (const float*)d_in[4];
  const float* W1  = (const float*)d_in[5];
  const float* b1  = (const float*)d_in[6];
  const float* pw  = (const float*)d_in[7];
  const float* Wu  = (const float*)d_in[8];
  const float* bu  = (const float*)d_in[9];
  const float* l0wih=(const float*)d_in[10];
  const float* l0whh=(const float*)d_in[11];
  const float* l0bih=(const float*)d_in[12];
  const float* l0bhh=(const float*)d_in[13];
  const float* lfwih=(const float*)d_in[14];
  const float* lfwhh=(const float*)d_in[15];
  const float* lfbih=(const float*)d_in[16];
  const float* lfbhh=(const float*)d_in[17];

  char* wp = (char*)d_ws;
  auto alloc = [&](size_t bytes)->char*{ char* p = wp; wp += ((bytes+255)/256)*256; return p; };
  float* A     = (float*)alloc((size_t)NN*64*4);   // h0 -> t2 -> xoacc
  float* B     = (float*)alloc((size_t)NN*64*4);   // x1acc -> agg -> xo
  float* C     = (float*)alloc((size_t)NN*64*4);   // x1
  float* D     = (float*)alloc((size_t)NN*64*4);   // res/y
  float* Ebuf  = (float*)alloc((size_t)NN*64*4);   // hp -> hy
  float* score = (float*)alloc((size_t)NN*4);
  float* dinv0 = (float*)alloc((size_t)NN*4);
  float* dinv1 = (float*)alloc((size_t)NN*4);
  unsigned long long* keys = (unsigned long long*)alloc((size_t)NN*8);
  int* degcnt  = (int*)alloc((size_t)NN*4);
  int* diagint = (int*)alloc((size_t)NN*4);
  int* ts      = (int*)alloc((size_t)NN*4);
  int* cs      = (int*)alloc((size_t)NN*4);
  int* kp      = (int*)alloc((size_t)NN*4);
  int* mlist   = (int*)alloc((size_t)NN*4);
  uint2* hash  = (uint2*)alloc((size_t)HASH_SIZE*8);
  unsigned* hist=(unsigned*)alloc((size_t)4*65536*4);
  unsigned* scal=(unsigned*)alloc(256);
  unsigned long long* selp = (unsigned long long*)(scal + 4);

  #define GRID1(n) dim3(((n)+255)/256), dim3(256), 0, stream
  const int N64 = NN*64;

  // init
  k_zero<<<GRID1(N64)>>>((unsigned*)B, N64);
  k_zero<<<GRID1(NN)>>>((unsigned*)degcnt, NN);
  k_zero<<<GRID1(NN)>>>((unsigned*)diagint, NN);
  k_zero<<<GRID1(NN)>>>((unsigned*)ts, NN);
  k_zero<<<GRID1(NN)>>>((unsigned*)cs, NN);
  k_zero<<<GRID1(4*65536)>>>(hist, 4*65536);
  k_init_scal<<<dim3(1),dim3(1),0,stream>>>(scal, selp);
  k_hash_init<<<GRID1(HASH_SIZE)>>>(hash);
  k_detect_mask<<<GRID1(NN/4)>>>((const int*)mp, scal);

  // GCN0
  k_mm_h0<<<GRID1(N64)>>>(x, W0, A);
  k_degcnt<<<GRID1(EE)>>>(col, degcnt);
  k_compact_mask<<<GRID1(NN)>>>(mp, scal, mlist);
  k_dinv0<<<GRID1(NN)>>>(degcnt, dinv0);
  k_gcn_agg<<<GRID1(EE*64)>>>(row, col, dinv0, A, B);
  k_gcn0_fin<<<GRID1(N64)>>>(B, A, dinv0, b0, C);

  // TopK selection (set only; labeling is equivariant)
  k_pwnorm<<<dim3(1),dim3(64),0,stream>>>(pw, (float*)scal);
  k_scorekey<<<dim3((NN+3)/4),dim3(256),0,stream>>>(C, pw, (const float*)scal, keys, score);
  for (int r=0;r<4;r++){
    k_hist<<<GRID1(NN)>>>(keys, hist + r*65536, selp, r);
    k_pick<<<dim3(1),dim3(256),0,stream>>>(hist + r*65536, selp, scal);
  }
  k_kpmark<<<GRID1(NN)>>>(keys, selp, kp);

  // (A+I)^2 diagonal via reverse-edge hash
  k_hash_build<<<GRID1(EE)>>>(row, col, hash);
  k_diag<<<GRID1(EE)>>>(row, col, hash, diagint);

  // pooled degree: colsum_c = sum_{r kept} A2[r,c] via two scalar SpMVs
  k_ts<<<GRID1(EE+NN)>>>(row, col, kp, ts);
  k_colsum<<<GRID1(EE+NN)>>>(row, col, ts, cs);
  k_dinv1<<<GRID1(NN)>>>(cs, diagint, kp, dinv1);

  // pooled GCN: hp = (x1*score)@W1 (kept), then two feature SpMV passes
  k_zero<<<GRID1(N64)>>>((unsigned*)A, N64);
  k_zero<<<GRID1(N64)>>>((unsigned*)B, N64);
  k_mm64s<<<GRID1(N64)>>>(C, W1, score, kp, Ebuf);
  k_t2<<<GRID1((EE+NN)*64)>>>(row, col, kp, dinv1, Ebuf, A);
  k_agg2<<<GRID1((EE+NN)*64)>>>(row, col, A, B);

  // res = x1 with masked rows <- LSTM0(x1 windows)
  k_copy<<<GRID1(N64)>>>(C, D);
  k_lstm<<<dim3(LSTM_G),dim3(256),0,stream>>>(C, D, mlist, scal, l0wih, l0whh, l0bih, l0bhh);

  // y = res + up (x2 written in place at kept nodes)
  k_y<<<GRID1(N64)>>>(B, Ebuf, dinv1, diagint, kp, b1, D);

  // up-GCN (same graph as GCN0, no relu) -> xo (B) and d_out
  k_mm64<<<GRID1(N64)>>>(D, Wu, Ebuf);
  k_zero<<<GRID1(N64)>>>((unsigned*)A, N64);
  k_gcn_agg<<<GRID1(EE*64)>>>(row, col, dinv0, Ebuf, A);
  k_xofin<<<GRID1(N64)>>>(A, Ebuf, dinv0, bu, B, (float*)d_out);

  // final LSTM on xo windows, scatter into d_out masked rows
  k_lstm<<<dim3(LSTM_G),dim3(256),0,stream>>>(B, (float*)d_out, mlist, scal, lfwih, lfwhh, lfbih, lfbhh);
  #undef GRID1
}

// Round 3
// 993.642 us; speedup vs baseline: 11.6874x; 1.3470x over previous
//
#include <hip/hip_runtime.h>
#include <math.h>

// Problem constants (fixed by reference setup)
#define NN 50000
#define EE 400000
#define CINV 32
#define KKEEP 25000          // ceil(0.5*N)
#define SEQL 5
#define HASH_BITS 20
#define HASH_SIZE (1u<<HASH_BITS)
#define HASH_MASK (HASH_SIZE-1u)
#define HEMPTY 0xFFFFFFFFu
#define LSTM_G 1024
#define PSB 196              // ceil(NN/256)

typedef float vf4 __attribute__((ext_vector_type(4)));

__device__ __forceinline__ float sigm(float x){ return 1.f/(1.f+__expf(-x)); }

// ---------------- utility ----------------
__global__ void k_zero(unsigned* __restrict__ p, int n){
  int i = blockIdx.x*256 + threadIdx.x;
  if (i < n) p[i] = 0u;
}
__global__ void k_init_scal(unsigned* scal, unsigned long long* selp){
  scal[0] = 0u;        // mcount
  scal[1] = 0u;        // mask-is-u8 flag
  scal[3] = KKEEP;     // radix-select remaining rank
  selp[0] = 0ull;      // radix-select prefix
}
__global__ void k_hash_init(uint2* tab){
  int i = blockIdx.x*256 + threadIdx.x;
  if (i < (int)HASH_SIZE) tab[i] = make_uint2(HEMPTY, 0u);
}
__global__ void k_detect_mask(const int* __restrict__ mp, unsigned* scal){
  int i = blockIdx.x*256 + threadIdx.x;
  if (i < NN/4){ if ((unsigned)mp[i] > 1u) atomicOr(&scal[1], 1u); }
}
__global__ void k_compact_mask(const void* __restrict__ mp, unsigned* scal, int* __restrict__ mlist){
  int i = blockIdx.x*256 + threadIdx.x;
  if (i >= NN) return;
  int mv = scal[1] ? (int)((const unsigned char*)mp)[i] : ((const int*)mp)[i];
  if (mv){ int p = (int)atomicAdd(&scal[0], 1u); mlist[p] = i; }
}
__global__ void k_copy(const float* __restrict__ s, float* __restrict__ d){
  int i = blockIdx.x*256 + threadIdx.x;
  if (i < NN*64) d[i] = s[i];
}

// ---------------- matmuls (float4 outputs) ----------------
__global__ void k_mm_h0v(const float* __restrict__ X, const float* __restrict__ W, float* __restrict__ Y){
  int idx = blockIdx.x*256 + threadIdx.x;
  if (idx >= NN*16) return;
  int i = idx>>4, fq = idx&15;
  const vf4* X4 = (const vf4*)&X[i*CINV];
  const vf4* W4 = (const vf4*)W;
  vf4 acc = {0.f,0.f,0.f,0.f};
  #pragma unroll
  for (int kq=0;kq<CINV/4;kq++){
    vf4 xv = X4[kq];
    #pragma unroll
    for (int u=0;u<4;u++) acc += xv[u] * W4[(kq*4+u)*16+fq];
  }
  ((vf4*)Y)[i*16+fq] = acc;
}
__global__ void k_mm64v(const float* __restrict__ X, const float* __restrict__ W, float* __restrict__ Y){
  int idx = blockIdx.x*256 + threadIdx.x;
  if (idx >= NN*16) return;
  int i = idx>>4, fq = idx&15;
  const vf4* X4 = (const vf4*)&X[i*64];
  const vf4* W4 = (const vf4*)W;
  vf4 acc = {0.f,0.f,0.f,0.f};
  #pragma unroll
  for (int kq=0;kq<16;kq++){
    vf4 xv = X4[kq];
    #pragma unroll
    for (int u=0;u<4;u++) acc += xv[u] * W4[(kq*4+u)*16+fq];
  }
  ((vf4*)Y)[i*16+fq] = acc;
}
__global__ void k_mm64sv(const float* __restrict__ X, const float* __restrict__ W,
                         const float* __restrict__ sc, const int* __restrict__ kp,
                         float* __restrict__ Y){
  int idx = blockIdx.x*256 + threadIdx.x;
  if (idx >= NN*16) return;
  int i = idx>>4, fq = idx&15;
  if (!kp[i]) return;
  const vf4* X4 = (const vf4*)&X[i*64];
  const vf4* W4 = (const vf4*)W;
  vf4 acc = {0.f,0.f,0.f,0.f};
  #pragma unroll
  for (int kq=0;kq<16;kq++){
    vf4 xv = X4[kq];
    #pragma unroll
    for (int u=0;u<4;u++) acc += xv[u] * W4[(kq*4+u)*16+fq];
  }
  float s = sc[i];
  acc *= s;
  ((vf4*)Y)[i*16+fq] = acc;
}

// ---------------- degree + CSR build ----------------
__global__ void k_degcnt(const int* __restrict__ col, int* __restrict__ degcnt){
  int e = blockIdx.x*256 + threadIdx.x;
  if (e < EE) atomicAdd(&degcnt[col[e]], 1);
}
__global__ void k_dinv0(const int* __restrict__ degcnt, float* __restrict__ dinv){
  int i = blockIdx.x*256 + threadIdx.x;
  if (i < NN) dinv[i] = rsqrtf((float)degcnt[i] + 2.0f);
}
// hierarchical exclusive prefix sum over degcnt -> indptr
__global__ void k_psum1(const int* __restrict__ deg, int* __restrict__ part, int* __restrict__ bsum){
  __shared__ int sc[256];
  int b = blockIdx.x, t = threadIdx.x, i = b*256+t;
  int v = (i<NN) ? deg[i] : 0;
  sc[t] = v; __syncthreads();
  for (int o=1;o<256;o<<=1){
    int x = (t>=o) ? sc[t-o] : 0;
    __syncthreads();
    sc[t] += x;
    __syncthreads();
  }
  if (i < NN) part[i] = sc[t]-v;       // exclusive within block
  if (t == 255) bsum[b] = sc[255];
}
__global__ void k_psum2(const int* __restrict__ bsum, int* __restrict__ boff){
  __shared__ int sc[256];
  int t = threadIdx.x;
  int v = (t<PSB) ? bsum[t] : 0;
  sc[t] = v; __syncthreads();
  for (int o=1;o<256;o<<=1){
    int x = (t>=o) ? sc[t-o] : 0;
    __syncthreads();
    sc[t] += x;
    __syncthreads();
  }
  if (t < PSB) boff[t] = sc[t]-v;
}
__global__ void k_psum3(const int* __restrict__ part, const int* __restrict__ boff, int* __restrict__ indptr){
  int i = blockIdx.x*256 + threadIdx.x;
  if (i < NN) indptr[i] = part[i] + boff[blockIdx.x];
  if (i == 0) indptr[NN] = EE;
}
__global__ void k_csr_fill(const int* __restrict__ row, const int* __restrict__ col,
                           const int* __restrict__ indptr, int* __restrict__ fillc,
                           int* __restrict__ csr_r){
  int e = blockIdx.x*256 + threadIdx.x;
  if (e >= EE) return;
  int c = col[e];
  int pos = indptr[c] + atomicAdd(&fillc[c], 1);
  csr_r[pos] = row[e];
}

// ---------------- CSR gather GCN kernels (wave per node) ----------------
__global__ void g_gcn0(const int* __restrict__ indptr, const int* __restrict__ csr_r,
                       const float* __restrict__ dinv, const float* __restrict__ H,
                       const float* __restrict__ b, float* __restrict__ out){
  int node = blockIdx.x*4 + (threadIdx.x>>6), lane = threadIdx.x&63;
  if (node >= NN) return;
  int s = __builtin_amdgcn_readfirstlane(indptr[node]);
  int e = __builtin_amdgcn_readfirstlane(indptr[node+1]);
  float acc = 0.f;
  for (int j=s;j<e;j++){
    int r = __builtin_amdgcn_readfirstlane(csr_r[j]);
    acc += dinv[r]*H[r*64+lane];
  }
  float di = dinv[node];
  float v = di*acc + 2.f*di*di*H[node*64+lane] + b[lane];
  out[node*64+lane] = fmaxf(v, 0.f);
}
// t2[c] = sum_{r->c in A+I} dinv1[r]*hp[r]  (dinv1=0 encodes "not kept")
__global__ void g_t2(const int* __restrict__ indptr, const int* __restrict__ csr_r,
                     const float* __restrict__ dinv1, const float* __restrict__ hp,
                     float* __restrict__ t2){
  int node = blockIdx.x*4 + (threadIdx.x>>6), lane = threadIdx.x&63;
  if (node >= NN) return;
  int s = __builtin_amdgcn_readfirstlane(indptr[node]);
  int e = __builtin_amdgcn_readfirstlane(indptr[node+1]);
  float acc = dinv1[node]*hp[node*64+lane];        // self loop
  for (int j=s;j<e;j++){
    int r = __builtin_amdgcn_readfirstlane(csr_r[j]);
    float dr = dinv1[r];
    if (dr != 0.f) acc += dr*hp[r*64+lane];
  }
  t2[node*64+lane] = acc;
}
// agg[c] = sum_{r->c in A+I} t2[r]; then D += relu(x2) at kept c
__global__ void g_agg2y(const int* __restrict__ indptr, const int* __restrict__ csr_r,
                        const float* __restrict__ t2, const float* __restrict__ hp,
                        const float* __restrict__ dinv1, const int* __restrict__ diagint,
                        const int* __restrict__ kp, const float* __restrict__ b1,
                        float* __restrict__ D){
  int node = blockIdx.x*4 + (threadIdx.x>>6), lane = threadIdx.x&63;
  if (node >= NN) return;
  if (!kp[node]) return;
  int s = __builtin_amdgcn_readfirstlane(indptr[node]);
  int e = __builtin_amdgcn_readfirstlane(indptr[node+1]);
  float acc = t2[node*64+lane];                    // self loop
  for (int j=s;j<e;j++){
    int r = __builtin_amdgcn_readfirstlane(csr_r[j]);
    acc += t2[r*64+lane];
  }
  float di = dinv1[node], hv = hp[node*64+lane];
  float diag = (float)(diagint[node] + 1);
  float v = di*(acc - diag*di*hv) + 2.f*di*di*hv + b1[lane];
  D[node*64+lane] += fmaxf(v, 0.f);
}
// up-GCN (no relu): writes xo (B) and d_out
__global__ void g_up(const int* __restrict__ indptr, const int* __restrict__ csr_r,
                     const float* __restrict__ dinv, const float* __restrict__ H,
                     const float* __restrict__ b, float* __restrict__ xo, float* __restrict__ out){
  int node = blockIdx.x*4 + (threadIdx.x>>6), lane = threadIdx.x&63;
  if (node >= NN) return;
  int s = __builtin_amdgcn_readfirstlane(indptr[node]);
  int e = __builtin_amdgcn_readfirstlane(indptr[node+1]);
  float acc = 0.f;
  for (int j=s;j<e;j++){
    int r = __builtin_amdgcn_readfirstlane(csr_r[j]);
    acc += dinv[r]*H[r*64+lane];
  }
  float di = dinv[node];
  float v = di*acc + 2.f*di*di*H[node*64+lane] + b[lane];
  xo[node*64+lane] = v; out[node*64+lane] = v;
}

// ---------------- TopK selection ----------------
__global__ void k_pwnorm(const float* __restrict__ pw, float* scalf){
  int lane = threadIdx.x;
  float v = pw[lane]*pw[lane];
  for (int o=32;o;o>>=1) v += __shfl_down(v, o, 64);
  if (lane==0) scalf[2] = sqrtf(v);
}
__global__ void k_scorekey(const float* __restrict__ x1, const float* __restrict__ pw,
                           const float* __restrict__ scalf,
                           unsigned long long* __restrict__ keys, float* __restrict__ score){
  int node = blockIdx.x*4 + (threadIdx.x>>6);
  int lane = threadIdx.x & 63;
  if (node >= NN) return;
  float v = x1[node*64+lane]*pw[lane];
  for (int o=32;o;o>>=1) v += __shfl_down(v, o, 64);
  if (lane==0){
    float s = tanhf(v / scalf[2]);
    s = s + 0.0f;                 // canonicalize -0 -> +0
    score[node] = s;
    unsigned u = __float_as_uint(s);
    unsigned asc = (u>>31) ? ~u : (u | 0x80000000u);
    unsigned desc = ~asc;
    keys[node] = (((unsigned long long)desc)<<32) | (unsigned)node;
  }
}
__global__ void k_hist(const unsigned long long* __restrict__ keys, unsigned* __restrict__ hist,
                       const unsigned long long* __restrict__ selp, int round){
  int i = blockIdx.x*256 + threadIdx.x;
  if (i >= NN) return;
  unsigned long long key = keys[i];
  int shift = 48 - 16*round;
  if (round==0 || (key>>(shift+16)) == selp[0])
    atomicAdd(&hist[(unsigned)((key>>shift)&0xFFFFull)], 1u);
}
__global__ void k_pick(const unsigned* __restrict__ hist, unsigned long long* selp, unsigned* scal){
  __shared__ unsigned csum[256];
  __shared__ unsigned bins[256];
  __shared__ int schunk;
  int t = threadIdx.x;
  const uint4* h4 = (const uint4*)(hist + t*256);
  unsigned s = 0;
  #pragma unroll 8
  for (int j=0;j<64;j++){ uint4 v = h4[j]; s += v.x+v.y+v.z+v.w; }
  csum[t] = s;
  __syncthreads();
  if (t==0){
    unsigned rem = scal[3];
    int chunk = 255;
    for (int c2=0;c2<256;c2++){ unsigned cc=csum[c2]; if (rem>cc) rem-=cc; else { chunk=c2; break; } }
    schunk = chunk; scal[3] = rem;
  }
  __syncthreads();
  bins[t] = hist[schunk*256 + t];
  __syncthreads();
  if (t==0){
    unsigned rem = scal[3];
    int bin = schunk*256 + 255;
    for (int b=0;b<256;b++){ unsigned hv=bins[b]; if (rem>hv) rem-=hv; else { bin = schunk*256 + b; break; } }
    selp[0] = (selp[0]<<16) | (unsigned long long)(unsigned)bin;
    scal[3] = rem;
  }
}
__global__ void k_kpmark(const unsigned long long* __restrict__ keys,
                         const unsigned long long* __restrict__ selp, int* __restrict__ kp){
  int i = blockIdx.x*256 + threadIdx.x;
  if (i < NN) kp[i] = (keys[i] <= selp[0]) ? 1 : 0;
}

// ---------------- reverse-edge hash (A^2 diagonal) ----------------
__global__ void k_hash_build(const int* __restrict__ row, const int* __restrict__ col, uint2* __restrict__ tab){
  int e = blockIdx.x*256 + threadIdx.x;
  if (e >= EE) return;
  unsigned key = (unsigned)row[e]*50000u + (unsigned)col[e];
  unsigned h = (key*2654435761u) >> (32-HASH_BITS);
  for(;;){
    unsigned old = atomicCAS(&tab[h].x, HEMPTY, key);
    if (old==HEMPTY || old==key){ atomicAdd(&tab[h].y, 1u); return; }
    h = (h+1)&HASH_MASK;
  }
}
__global__ void k_diag(const int* __restrict__ row, const int* __restrict__ col,
                       const uint2* __restrict__ tab, int* __restrict__ diagint){
  int e = blockIdx.x*256 + threadIdx.x;
  if (e >= EE) return;
  unsigned rkey = (unsigned)col[e]*50000u + (unsigned)row[e];
  unsigned h = (rkey*2654435761u) >> (32-HASH_BITS);
  for(;;){
    unsigned kk = tab[h].x;
    if (kk==rkey){ atomicAdd(&diagint[row[e]], (int)tab[h].y); return; }
    if (kk==HEMPTY) return;
    h = (h+1)&HASH_MASK;
  }
}

// ---------------- pooled-graph degree via two scalar SpMVs ----------------
__global__ void k_ts(const int* __restrict__ row, const int* __restrict__ col,
                     const int* __restrict__ kp, int* __restrict__ ts){
  int idx = blockIdx.x*256 + threadIdx.x;
  if (idx < EE){ if (kp[row[idx]]) atomicAdd(&ts[col[idx]], 1); }
  else { int i = idx-EE; if (i < NN && kp[i]) atomicAdd(&ts[i], 1); }
}
__global__ void k_colsum(const int* __restrict__ row, const int* __restrict__ col,
                         const int* __restrict__ ts, int* __restrict__ cs){
  int idx = blockIdx.x*256 + threadIdx.x;
  if (idx < EE){ int v = ts[row[idx]]; if (v) atomicAdd(&cs[col[idx]], v); }
  else { int i = idx-EE; if (i < NN){ int v = ts[i]; if (v) atomicAdd(&cs[i], v); } }
}
__global__ void k_dinv1(const int* __restrict__ cs, const int* __restrict__ diagint,
                        const int* __restrict__ kp, float* __restrict__ dinv1){
  int i = blockIdx.x*256 + threadIdx.x;
  if (i >= NN) return;
  dinv1[i] = kp[i] ? rsqrtf((float)(cs[i] - diagint[i] - 1) + 2.0f) : 0.f;
}

// ---------------- fused 5-step LSTM: weights pinned in VGPRs via asm ----------------
// Wave w owns gate chunk w; lane g holds row w*64+g of W_ih/W_hh (32 float4,
// asm-pinned so the compiler cannot re-load them inside the loop). 2 nodes per
// block; t=0 skips the hh half (h=0); epilogue split wave0/node0, wave1/node1.
__global__ __launch_bounds__(256) void k_lstm(const float* __restrict__ src, float* __restrict__ dst,
                       const int* __restrict__ mlist, const unsigned* __restrict__ scal,
                       const float* __restrict__ wih, const float* __restrict__ whh,
                       const float* __restrict__ bih, const float* __restrict__ bhh){
  int M = (int)scal[0];
  int w = threadIdx.x>>6, lane = threadIdx.x&63;
  int r = w*64 + lane;
  const vf4* gih = (const vf4*)&wih[r*64];
  const vf4* ghh = (const vf4*)&whh[r*64];
  vf4 wi[16], wh[16];
  #pragma unroll
  for (int j=0;j<16;j++){ wi[j]=gih[j]; wh[j]=ghh[j]; }
  #pragma unroll
  for (int j=0;j<16;j++){ asm volatile("" : "+v"(wi[j]), "+v"(wh[j])); }
  float bq = bih[r] + bhh[r];

  __shared__ float sx[2][SEQL][64];      // [node][t][feat]
  __shared__ float sh[2][64];            // [node][feat]
  __shared__ float gates[2][4][64];      // [node][chunk][elem]

  for (int p = blockIdx.x; 2*p < M; p += LSTM_G){
    int m0 = 2*p, m1 = 2*p+1;
    bool v1 = (m1 < M);
    int n0 = mlist[m0];
    int n1 = v1 ? mlist[m1] : n0;
    for (int idx = threadIdx.x; idx < 2*SEQL*64; idx += 256){
      int nd = idx >= SEQL*64;
      int rem = idx - nd*SEQL*64;
      int rr = rem >> 6, ff = rem & 63;
      int node = nd ? n1 : n0;
      int ti = node - (SEQL-1) + rr;
      sx[nd][rr][ff] = (ti >= 0) ? src[ti*64 + ff] : 0.f;
    }
    __syncthreads();
    float c0=0.f, c1=0.f, h0v=0.f, h1v=0.f;
    // ---- t = 0: h == 0, xg only ----
    {
      float a0 = bq, a1 = bq;
      #pragma unroll
      for (int j=0;j<16;j++){
        vf4 x0 = *(const vf4*)&sx[0][0][j*4];
        a0 += x0.x*wi[j].x + x0.y*wi[j].y + x0.z*wi[j].z + x0.w*wi[j].w;
        vf4 x1 = *(const vf4*)&sx[1][0][j*4];
        a1 += x1.x*wi[j].x + x1.y*wi[j].y + x1.z*wi[j].z + x1.w*wi[j].w;
      }
      gates[0][w][lane] = a0;
      gates[1][w][lane] = a1;
      __syncthreads();
      if (w==0){
        float gi=gates[0][0][lane], gg=gates[0][2][lane], go=gates[0][3][lane];
        c0 = sigm(gi)*tanhf(gg);
        h0v = sigm(go)*tanhf(c0);
        sh[0][lane] = h0v;
      } else if (w==1){
        float gi=gates[1][0][lane], gg=gates[1][2][lane], go=gates[1][3][lane];
        c1 = sigm(gi)*tanhf(gg);
        h1v = sigm(go)*tanhf(c1);
        sh[1][lane] = h1v;
      }
      __syncthreads();
    }
    // ---- t = 1..4 ----
    for (int t=1;t<SEQL;t++){
      float a0 = bq, a1 = bq;
      #pragma unroll
      for (int j=0;j<16;j++){
        vf4 x0 = *(const vf4*)&sx[0][t][j*4];
        vf4 hh0 = *(const vf4*)&sh[0][j*4];
        a0 += x0.x*wi[j].x + x0.y*wi[j].y + x0.z*wi[j].z + x0.w*wi[j].w
            + hh0.x*wh[j].x + hh0.y*wh[j].y + hh0.z*wh[j].z + hh0.w*wh[j].w;
        vf4 x1 = *(const vf4*)&sx[1][t][j*4];
        vf4 hh1 = *(const vf4*)&sh[1][j*4];
        a1 += x1.x*wi[j].x + x1.y*wi[j].y + x1.z*wi[j].z + x1.w*wi[j].w
            + hh1.x*wh[j].x + hh1.y*wh[j].y + hh1.z*wh[j].z + hh1.w*wh[j].w;
      }
      gates[0][w][lane] = a0;
      gates[1][w][lane] = a1;
      __syncthreads();
      if (w==0){
        float gi=gates[0][0][lane], gf=gates[0][1][lane], gg=gates[0][2][lane], go=gates[0][3][lane];
        c0 = sigm(gf)*c0 + sigm(gi)*tanhf(gg);
        h0v = sigm(go)*tanhf(c0);
        sh[0][lane] = h0v;
      } else if (w==1){
        float gi=gates[1][0][lane], gf=gates[1][1][lane], gg=gates[1][2][lane], go=gates[1][3][lane];
        c1 = sigm(gf)*c1 + sigm(gi)*tanhf(gg);
        h1v = sigm(go)*tanhf(c1);
        sh[1][lane] = h1v;
      }
      __syncthreads();
    }
    if (w==0) dst[n0*64+lane] = h0v;
    if (w==1 && v1) dst[n1*64+lane] = h1v;
    __syncthreads();   // all waves done with sx/gates before next pair
  }
}

// ==========================================================================
extern "C" void kernel_launch(void* const* d_in, const int* in_sizes, int n_in,
                              void* d_out, int out_size, void* d_ws, size_t ws_size,
                              hipStream_t stream) {
  const float* x   = (const float*)d_in[0];
  const int*   ei  = (const int*)d_in[1];
  const int*   row = ei;
  const int*   col = ei + EE;
  const void*  mp  = d_in[2];
  const float* W0  = (const float*)d_in[3];
  const float* b0  = (const float*)d_in[4];
  const float* W1  = (const float*)d_in[5];
  const float* b1  = (const float*)d_in[6];
  const float* pw  = (const float*)d_in[7];
  const float* Wu  = (const float*)d_in[8];
  const float* bu  = (const float*)d_in[9];
  const float* l0wih=(const float*)d_in[10];
  const float* l0whh=(const float*)d_in[11];
  const float* l0bih=(const float*)d_in[12];
  const float* l0bhh=(const float*)d_in[13];
  const float* lfwih=(const float*)d_in[14];
  const float* lfwhh=(const float*)d_in[15];
  const float* lfbih=(const float*)d_in[16];
  const float* lfbhh=(const float*)d_in[17];

  char* wp = (char*)d_ws;
  auto alloc = [&](size_t bytes)->char*{ char* p = wp; wp += ((bytes+255)/256)*256; return p; };
  float* A     = (float*)alloc((size_t)NN*64*4);   // h0 -> t2
  float* B     = (float*)alloc((size_t)NN*64*4);   // xo
  float* C     = (float*)alloc((size_t)NN*64*4);   // x1
  float* D     = (float*)alloc((size_t)NN*64*4);   // res/y
  float* Ebuf  = (float*)alloc((size_t)NN*64*4);   // hp -> up-GCN input
  float* score = (float*)alloc((size_t)NN*4);
  float* dinv0 = (float*)alloc((size_t)NN*4);
  float* dinv1 = (float*)alloc((size_t)NN*4);
  unsigned long long* keys = (unsigned long long*)alloc((size_t)NN*8);
  int* degcnt  = (int*)alloc((size_t)NN*4);
  int* diagint = (int*)alloc((size_t)NN*4);
  int* ts      = (int*)alloc((size_t)NN*4);
  int* cs      = (int*)alloc((size_t)NN*4);
  int* kp      = (int*)alloc((size_t)NN*4);
  int* mlist   = (int*)alloc((size_t)NN*4);
  int* indptr  = (int*)alloc((size_t)(NN+1)*4);
  int* part    = (int*)alloc((size_t)NN*4);
  int* fillc   = (int*)alloc((size_t)NN*4);
  int* bsum    = (int*)alloc((size_t)256*4);
  int* boff    = (int*)alloc((size_t)256*4);
  int* csr_r   = (int*)alloc((size_t)EE*4);
  uint2* hash  = (uint2*)alloc((size_t)HASH_SIZE*8);
  unsigned* hist=(unsigned*)alloc((size_t)4*65536*4);
  unsigned* scal=(unsigned*)alloc(256);
  unsigned long long* selp = (unsigned long long*)(scal + 4);

  #define GRID1(n) dim3(((n)+255)/256), dim3(256), 0, stream
  #define GRIDW dim3((NN+3)/4), dim3(256), 0, stream
  const int N64 = NN*64;

  // init
  k_zero<<<GRID1(NN)>>>((unsigned*)degcnt, NN);
  k_zero<<<GRID1(NN)>>>((unsigned*)diagint, NN);
  k_zero<<<GRID1(NN)>>>((unsigned*)ts, NN);
  k_zero<<<GRID1(NN)>>>((unsigned*)cs, NN);
  k_zero<<<GRID1(NN)>>>((unsigned*)fillc, NN);
  k_zero<<<GRID1(4*65536)>>>(hist, 4*65536);
  k_init_scal<<<dim3(1),dim3(1),0,stream>>>(scal, selp);
  k_hash_init<<<GRID1(HASH_SIZE)>>>(hash);
  k_detect_mask<<<GRID1(NN/4)>>>((const int*)mp, scal);

  // degree + CSR (by col)
  k_degcnt<<<GRID1(EE)>>>(col, degcnt);
  k_compact_mask<<<GRID1(NN)>>>(mp, scal, mlist);
  k_dinv0<<<GRID1(NN)>>>(degcnt, dinv0);
  k_psum1<<<dim3(PSB),dim3(256),0,stream>>>(degcnt, part, bsum);
  k_psum2<<<dim3(1),dim3(256),0,stream>>>(bsum, boff);
  k_psum3<<<dim3(PSB),dim3(256),0,stream>>>(part, boff, indptr);
  k_csr_fill<<<GRID1(EE)>>>(row, col, indptr, fillc, csr_r);

  // GCN0 (gather)
  k_mm_h0v<<<GRID1(NN*16)>>>(x, W0, A);
  g_gcn0<<<GRIDW>>>(indptr, csr_r, dinv0, A, b0, C);

  // TopK selection
  k_pwnorm<<<dim3(1),dim3(64),0,stream>>>(pw, (float*)scal);
  k_scorekey<<<GRIDW>>>(C, pw, (const float*)scal, keys, score);
  for (int r2=0;r2<4;r2++){
    k_hist<<<GRID1(NN)>>>(keys, hist + r2*65536, selp, r2);
    k_pick<<<dim3(1),dim3(256),0,stream>>>(hist + r2*65536, selp, scal);
  }
  k_kpmark<<<GRID1(NN)>>>(keys, selp, kp);

  // (A+I)^2 diagonal via reverse-edge hash
  k_hash_build<<<GRID1(EE)>>>(row, col, hash);
  k_diag<<<GRID1(EE)>>>(row, col, hash, diagint);

  // pooled degree
  k_ts<<<GRID1(EE+NN)>>>(row, col, kp, ts);
  k_colsum<<<GRID1(EE+NN)>>>(row, col, ts, cs);
  k_dinv1<<<GRID1(NN)>>>(cs, diagint, kp, dinv1);

  // pooled GCN: hp then two gather passes
  k_mm64sv<<<GRID1(NN*16)>>>(C, W1, score, kp, Ebuf);
  g_t2<<<GRIDW>>>(indptr, csr_r, dinv1, Ebuf, A);

  // res = x1 with masked rows <- LSTM0(x1 windows)
  k_copy<<<GRID1(N64)>>>(C, D);
  k_lstm<<<dim3(LSTM_G),dim3(256),0,stream>>>(C, D, mlist, scal, l0wih, l0whh, l0bih, l0bhh);

  // y = res + up (fused epilogue)
  g_agg2y<<<GRIDW>>>(indptr, csr_r, A, Ebuf, dinv1, diagint, kp, b1, D);

  // up-GCN -> xo (B) and d_out
  k_mm64v<<<GRID1(NN*16)>>>(D, Wu, Ebuf);
  g_up<<<GRIDW>>>(indptr, csr_r, dinv0, Ebuf, bu, B, (float*)d_out);

  // final LSTM on xo windows, scatter into d_out masked rows
  k_lstm<<<dim3(LSTM_G),dim3(256),0,stream>>>(B, (float*)d_out, mlist, scal, lfwih, lfwhh, lfbih, lfbhh);
  #undef GRIDW
  #undef GRID1
}